// Round 14
// baseline (607.675 us; speedup 1.0000x reference)
//
#include <hip/hip_runtime.h>

#define NBATCH 16
#define CCH 256
#define NTOK 2304

typedef __attribute__((ext_vector_type(8))) short bf16x8;
typedef __attribute__((ext_vector_type(4))) short bf16x4v;
typedef __attribute__((ext_vector_type(4))) float f32x4;

__device__ __forceinline__ short f2bf(float x){
  unsigned u = __builtin_bit_cast(unsigned, x);
  u = u + 0x7FFFu + ((u >> 16) & 1u);
  return (short)(u >> 16);
}
__device__ __forceinline__ float bf2f(short h){
  unsigned u = ((unsigned)(unsigned short)h) << 16;
  return __builtin_bit_cast(float, u);
}
__device__ __forceinline__ unsigned char f2fp8(float v){
  return (unsigned char)(__builtin_amdgcn_cvt_pk_fp8_f32(v, v, 0, false) & 0xff);
}

__device__ __forceinline__ void gld_lds16(const void* g, void* l){
  __builtin_amdgcn_global_load_lds((const __attribute__((address_space(1))) void*)g,
                                   (__attribute__((address_space(3))) void*)l, 16, 0, 0);
}

// ---------------- weights fp32 -> bf16 ----------------
__global__ __launch_bounds__(256) void cw_kernel(const float* __restrict__ Wq, const float* __restrict__ Wk,
                                                 const float* __restrict__ Wv, const float* __restrict__ Wo,
                                                 short* __restrict__ out){
  int idx = blockIdx.x * 256 + threadIdx.x;
  int which = idx >> 14;
  int off = idx & 16383;
  const float* src = which==0 ? Wq : which==1 ? Wk : which==2 ? Wv : Wo;
  float4 v = ((const float4*)src)[off];
  bf16x4v pk = { f2bf(v.x), f2bf(v.y), f2bf(v.z), f2bf(v.w) };
  *(bf16x4v*)(out + ((size_t)which << 16) + ((size_t)off << 2)) = pk;
}

// ---------------- transpose+convert [C][N] f32 -> [N][C] bf16 ----------------
__global__ __launch_bounds__(256) void prep_kernel(const float* __restrict__ img, const float* __restrict__ msk,
                                                   short* __restrict__ imgT, short* __restrict__ mskT){
  int zz = blockIdx.z; int b = zz >> 1; int which = zz & 1;
  const float* src = (which ? msk : img) + (size_t)b * CCH * NTOK;
  short* dst = (which ? mskT : imgT) + (size_t)b * NTOK * CCH;
  int n0 = blockIdx.x * 64, c0 = blockIdx.y * 64;
  __shared__ __align__(16) short tile[64][72];
  int tid = threadIdx.x;
  int r = tid >> 2, g = tid & 3;
  const float* p = src + (size_t)(c0 + r) * NTOK + n0 + 16 * g;
  #pragma unroll
  for (int q4 = 0; q4 < 4; q4++){
    float4 v = *(const float4*)(p + 4 * q4);
    tile[16*g + 4*q4 + 0][r] = f2bf(v.x);
    tile[16*g + 4*q4 + 1][r] = f2bf(v.y);
    tile[16*g + 4*q4 + 2][r] = f2bf(v.z);
    tile[16*g + 4*q4 + 3][r] = f2bf(v.w);
  }
  __syncthreads();
  short* qp = dst + (size_t)(n0 + r) * CCH + c0 + 16 * g;
  *(bf16x8*)qp = *(const bf16x8*)&tile[r][16*g];
  *(bf16x8*)(qp + 8) = *(const bf16x8*)&tile[r][16*g + 8];
}

// ---------------- 128x128 GEMM core ----------------
__device__ __forceinline__ void gemm128(const short* __restrict__ Ablk, const short* __restrict__ Bblk,
                                        short* As, short* Bs, f32x4 (&acc)[4][4]){
  const int tid = threadIdx.x;
  const int l = tid & 63, w = tid >> 6;
  const int l15 = l & 15, lhi = l >> 4;
  const int wi = w >> 1, wj = w & 1;
  const int srow = tid >> 3, scs = tid & 7;
  const f32x4 z4 = {0.f, 0.f, 0.f, 0.f};
  #pragma unroll
  for (int mt = 0; mt < 4; mt++)
    #pragma unroll
    for (int nt = 0; nt < 4; nt++) acc[mt][nt] = z4;

  #pragma unroll 1
  for (int kt = 0; kt < 4; kt++){
    const int k0 = kt * 64;
    bf16x8 ra[4], rb[4];
    #pragma unroll
    for (int p = 0; p < 4; p++){
      const int row = p * 32 + srow;
      ra[p] = *(const bf16x8*)(Ablk + (size_t)row * CCH + k0 + 8 * scs);
      rb[p] = *(const bf16x8*)(Bblk + (size_t)row * CCH + k0 + 8 * scs);
    }
    __syncthreads();
    #pragma unroll
    for (int p = 0; p < 4; p++){
      const int row = p * 32 + srow;
      const int sw = (scs ^ (row & 7)) << 3;
      *(bf16x8*)(As + row * 64 + sw) = ra[p];
      *(bf16x8*)(Bs + row * 64 + sw) = rb[p];
    }
    __syncthreads();
    #pragma unroll
    for (int kk = 0; kk < 2; kk++){
      bf16x8 afr[4], bfr[4];
      #pragma unroll
      for (int mt = 0; mt < 4; mt++){
        const int row = 64 * wi + 16 * mt + l15;
        const int ch = 4 * kk + lhi;
        afr[mt] = *(const bf16x8*)(As + row * 64 + ((ch ^ (row & 7)) << 3));
      }
      #pragma unroll
      for (int nt = 0; nt < 4; nt++){
        const int row = 64 * wj + 16 * nt + l15;
        const int ch = 4 * kk + lhi;
        bfr[nt] = *(const bf16x8*)(Bs + row * 64 + ((ch ^ (row & 7)) << 3));
      }
      #pragma unroll
      for (int mt = 0; mt < 4; mt++)
        #pragma unroll
        for (int nt = 0; nt < 4; nt++)
          acc[mt][nt] = __builtin_amdgcn_mfma_f32_16x16x32_bf16(afr[mt], bfr[nt], acc[mt][nt], 0, 0, 0);
    }
  }
}

// ---------------- QKV projections ----------------
// Q/K outputs are fp8 e4m3 (natural scale; 1/sqrt(C)*log2e applied in attn exp2).
__global__ __launch_bounds__(256) void proj_kernel(const short* __restrict__ imgT, const short* __restrict__ mskT,
                                                   const short* __restrict__ Wb,
                                                   const float* __restrict__ bq, const float* __restrict__ bk,
                                                   const float* __restrict__ bv,
                                                   unsigned char* __restrict__ Q8, unsigned char* __restrict__ K8,
                                                   short* __restrict__ Vn){
  __shared__ __align__(16) short As[128 * 64];
  __shared__ __align__(16) short Bs[128 * 64];
  const int b = blockIdx.z, which = blockIdx.y, bx = blockIdx.x;
  const size_t nbT = (size_t)b * NTOK * CCH;
  const short* Ablk; const short* Bblk; const float* bias;
  int ti, tj;
  if (which == 0){
    ti = bx >> 1; tj = bx & 1;
    Ablk = mskT + nbT + (size_t)ti * 128 * CCH;
    Bblk = Wb + (size_t)tj * 128 * CCH;
    bias = bq;
  } else if (which == 1){
    ti = bx >> 1; tj = bx & 1;
    Ablk = imgT + nbT + (size_t)ti * 128 * CCH;
    Bblk = Wb + 65536 + (size_t)tj * 128 * CCH;
    bias = bk;
  } else {
    ti = bx / 18; tj = bx % 18;
    Ablk = Wb + 2 * 65536 + (size_t)ti * 128 * CCH;
    Bblk = imgT + nbT + (size_t)tj * 128 * CCH;
    bias = bv;
  }
  f32x4 acc[4][4];
  gemm128(Ablk, Bblk, As, Bs, acc);
  const int l = threadIdx.x & 63, w = threadIdx.x >> 6;
  const int l15 = l & 15, lhi = l >> 4, wi = w >> 1, wj = w & 1;
  if (which < 2){
    unsigned char* o8 = (which == 0 ? Q8 : K8) + nbT;
    #pragma unroll
    for (int mt = 0; mt < 4; mt++){
      const int i0 = ti * 128 + 64 * wi + 16 * mt + 4 * lhi;
      #pragma unroll
      for (int nt = 0; nt < 4; nt++){
        const int j = tj * 128 + 64 * wj + 16 * nt + l15;
        const float bj = bias[j];
        #pragma unroll
        for (int r = 0; r < 4; r++)
          o8[(size_t)(i0 + r) * CCH + j] = f2fp8(acc[mt][nt][r] + bj);
      }
    }
  } else {
    short* outp = Vn + nbT;
    #pragma unroll
    for (int mt = 0; mt < 4; mt++){
      const int i0 = ti * 128 + 64 * wi + 16 * mt + 4 * lhi;
      #pragma unroll
      for (int nt = 0; nt < 4; nt++){
        const int j = tj * 128 + 64 * wj + 16 * nt + l15;
        #pragma unroll
        for (int r = 0; r < 4; r++)
          outp[(size_t)(i0 + r) * NTOK + j] = f2bf(acc[mt][nt][r] + bias[i0 + r]);
      }
    }
  }
}

// ---------------- attention: fp8 swapped-QK^T, K double-buffer, split-KV x2 ----------------
// Same 2-sync R5 skeleton; K staged into alternating buffers with the issue at the
// TOP of the tile (after sync1) so stage latency is covered by V-load+QK+softmax
// before sync2's vmcnt drain. P packed via v_cvt_pk_bf16_f32 (register-only asm).
__global__ __launch_bounds__(256, 4) void attn_kernel(const unsigned char* __restrict__ Q8,
                                                      const unsigned char* __restrict__ K8,
                                                      const short* __restrict__ Vn,
                                                      short* __restrict__ Opart, float* __restrict__ lsumg){
  const int phys = blockIdx.x;
  const int L = (phys & 7) * 144 + (phys >> 3);   // 1152 = 8*144; 144 = 2 batches/XCD
  const int b = L / 72;
  const int rem = L % 72;
  const int half = rem / 36;
  const int q0 = (rem % 36) * 64;
  const int t0 = half * 18;
  const int tid = threadIdx.x, w = tid >> 6, l = tid & 63;
  const int l15 = l & 15, lhi = l >> 4;
  const unsigned char* Qb = Q8 + (size_t)b * NTOK * CCH;
  const unsigned char* Kb = K8 + (size_t)b * NTOK * CCH;
  const short* Vb = Vn + (size_t)b * CCH * NTOK;
  __shared__ __align__(16) unsigned char Ks8[2][64 * 256];  // 32 KB (fp8, dbuf)
  __shared__ __align__(16) short P_lds[64 * 64];            // 8 KB; total 40960 B

  const float SCL = 0.0625f * 1.44269504088896f;  // 1/sqrt(256) * log2(e)
  const int rs2 = (l15 & 7) << 1;                 // QK read row-swizzle (row&7 == l15&7)

  // Q fp8 fragments in registers (16 VGPR)
  long qf[8];
  {
    const unsigned char* qrow = Qb + (size_t)(q0 + 16 * w + l15) * CCH + 8 * lhi;
    #pragma unroll
    for (int kk = 0; kk < 8; kk++) qf[kk] = *(const long*)(qrow + 32 * kk);
  }
  const f32x4 z4 = {0.f, 0.f, 0.f, 0.f};
  f32x4 oacc[4][4];
  #pragma unroll
  for (int qt = 0; qt < 4; qt++)
    #pragma unroll
    for (int ct = 0; ct < 4; ct++) oacc[qt][ct] = z4;
  float lpart = 0.f;

  // stage: 16 slots x 1KB; slot covers rows 4s..4s+3; lane l -> row 4s+(l>>4),
  // src 16B-chunk c16 = (l&15) ^ (row&7); dest linear (rule 21).
#define STAGE_K(BUF, M0) do { \
    _Pragma("unroll") \
    for (int r = 0; r < 4; r++){ \
      const int slot = 4 * r + w; \
      const int row = 4 * slot + (l >> 4); \
      const int c16 = (l & 15) ^ (row & 7); \
      gld_lds16(Kb + (size_t)((M0) + row) * CCH + (c16 << 4), &Ks8[BUF][slot * 1024]); \
    } } while(0)

  STAGE_K(0, t0 * 64);

  int cur = 0;
  #pragma unroll 1
  for (int t = t0; t < t0 + 18; t++){
    const int m0 = t * 64;
    __syncthreads();   // sync1: K(t) staged (vmcnt drained at the PREVIOUS sync2 or here)

    // issue stage of K(t+1) into the other buffer: covered by V-load+QK+softmax
    if (t + 1 < t0 + 18) STAGE_K(cur ^ 1, m0 + 64);

    // prefetch V tile (bf16) into registers
    bf16x8 vfp[8];
    #pragma unroll
    for (int km = 0; km < 2; km++)
      #pragma unroll
      for (int ct = 0; ct < 4; ct++)
        vfp[4 * km + ct] = *(const bf16x8*)(Vb + (size_t)(64 * w + 16 * ct + l15) * NTOK + m0 + 32 * km + 8 * lhi);

    // S^T = K·Q^T (fp8, swapped operands): lane holds S[m=16mjb+4lhi+r][q=l15]
    const unsigned char* Kc = &Ks8[cur][0];
    f32x4 sacc[4] = {z4, z4, z4, z4};
    __builtin_amdgcn_s_setprio(1);
    #pragma unroll
    for (int mjb = 0; mjb < 4; mjb++){
      const int row = 16 * mjb + l15;
      #pragma unroll
      for (int kk = 0; kk < 8; kk++){
        const int c8 = (4 * kk + lhi) ^ rs2;
        long kf = *(const long*)(Kc + row * 256 + (c8 << 3));
        sacc[mjb] = __builtin_amdgcn_mfma_f32_16x16x32_fp8_fp8(kf, qf[kk], sacc[mjb], 0, 0, 0);
      }
    }
    __builtin_amdgcn_s_setprio(0);
    // P = exp2(s*SCL); in-lane partial row sum; packed b64 write via v_cvt_pk_bf16_f32
    {
      const int prow = 16 * w + l15;
      const int rsw = l15 & 7;
      #pragma unroll
      for (int mjb = 0; mjb < 4; mjb++){
        float p0 = exp2f(sacc[mjb][0] * SCL);
        float p1 = exp2f(sacc[mjb][1] * SCL);
        float p2 = exp2f(sacc[mjb][2] * SCL);
        float p3 = exp2f(sacc[mjb][3] * SCL);
        lpart += (p0 + p1) + (p2 + p3);
        unsigned u0, u1;
        asm("v_cvt_pk_bf16_f32 %0, %1, %2" : "=v"(u0) : "v"(p0), "v"(p1));
        asm("v_cvt_pk_bf16_f32 %0, %1, %2" : "=v"(u1) : "v"(p2), "v"(p3));
        uint2 uv = {u0, u1};
        const int ch16 = (2 * mjb + (lhi >> 1)) ^ rsw;
        *(uint2*)&P_lds[prow * 64 + (ch16 << 3) + ((lhi & 1) << 2)] = uv;
      }
    }
    __syncthreads();   // sync2: P visible; all Ks[cur] reads done; stage(t+1) drained

    // O += P · V^T (bf16)
    __builtin_amdgcn_s_setprio(1);
    #pragma unroll
    for (int km = 0; km < 2; km++){
      bf16x8 pf[4];
      #pragma unroll
      for (int qt = 0; qt < 4; qt++){
        const int prow = 16 * qt + l15;
        pf[qt] = *(const bf16x8*)&P_lds[prow * 64 + (((4 * km + lhi) ^ (prow & 7)) << 3)];
      }
      #pragma unroll
      for (int qt = 0; qt < 4; qt++)
        #pragma unroll
        for (int ct = 0; ct < 4; ct++)
          oacc[qt][ct] = __builtin_amdgcn_mfma_f32_16x16x32_bf16(pf[qt], vfp[4 * km + ct], oacc[qt][ct], 0, 0, 0);
    }
    __builtin_amdgcn_s_setprio(0);
    cur ^= 1;
  }
#undef STAGE_K

  const size_t hrow = ((size_t)half * NBATCH + b) * NTOK + q0;
  // q = q0 + 16w + l15; partials live in lanes {l, l^16, l^32, l^48}
  {
    float s = lpart;
    s += __shfl_xor(s, 16);
    s += __shfl_xor(s, 32);
    if (lhi == 0) lsumg[hrow + 16 * w + l15] = s;
  }
  short* Ob = Opart + hrow * CCH;
  #pragma unroll
  for (int qt = 0; qt < 4; qt++)
    #pragma unroll
    for (int ct = 0; ct < 4; ct++)
      #pragma unroll
      for (int r = 0; r < 4; r++)
        Ob[(size_t)(16 * qt + 4 * lhi + r) * CCH + 64 * w + 16 * ct + l15] = f2bf(oacc[qt][ct][r]);
}

// ================= final (fused reduce): out = img + Wo·((O0+O1)/l) + bo =================
__global__ __launch_bounds__(512, 4) void final_kernel(
    const float* __restrict__ Wo, const float* __restrict__ bo,
    const short* __restrict__ Op, const float* __restrict__ ls,
    const float* __restrict__ img, float* __restrict__ out){
  __shared__ __align__(16) short XL[128 * 72];   // combined av tile [n][c]
  __shared__ __align__(16) short WL[256 * 64];
  const int ti = blockIdx.x, b = blockIdx.y;
  const int n0 = ti * 128;
  const int t = threadIdx.x, wv = t >> 6, l = t & 63;
  const int l15 = l & 15, lhi = l >> 4;
  const int sn = t >> 2, sj = t & 3;
  const int so = t >> 1, sh = t & 1;
  const size_t HS = (size_t)NBATCH * NTOK * CCH;
  const size_t row = (size_t)b * NTOK + n0 + sn;
  const float inv = 1.0f / (ls[row] + ls[(size_t)NBATCH * NTOK + row]);

  const f32x4 z4 = {0.f, 0.f, 0.f, 0.f};
  f32x4 acc[4][4];
  #pragma unroll
  for (int mt = 0; mt < 4; mt++)
    #pragma unroll
    for (int nt = 0; nt < 4; nt++) acc[mt][nt] = z4;

  #pragma unroll 1
  for (int kt = 0; kt < 4; kt++){
    const int c0 = kt * 64;
    bf16x8 a0[2], a1[2];
    #pragma unroll
    for (int j = 0; j < 2; j++){
      const int c = c0 + (2 * sj + j) * 8;
      a0[j] = *(const bf16x8*)(Op + row * CCH + c);
      a1[j] = *(const bf16x8*)(Op + HS + row * CCH + c);
    }
    float4 wreg[8];
    #pragma unroll
    for (int q = 0; q < 8; q++)
      wreg[q] = *(const float4*)(Wo + (size_t)so * CCH + c0 + 32 * sh + 4 * q);
    __syncthreads();
    #pragma unroll
    for (int j = 0; j < 2; j++){
      const int ch = 2 * sj + j;
      bf16x8 cb;
      #pragma unroll
      for (int e = 0; e < 8; e++)
        cb[e] = f2bf((bf2f(a0[j][e]) + bf2f(a1[j][e])) * inv);
      *(bf16x8*)&XL[sn * 72 + ((ch ^ ((sn >> 4) & 7)) << 3)] = cb;
    }
    #pragma unroll
    for (int q = 0; q < 8; q++){
      const int cl = 32 * sh + 4 * q;
      bf16x4v pk = { f2bf(wreg[q].x), f2bf(wreg[q].y), f2bf(wreg[q].z), f2bf(wreg[q].w) };
      *(bf16x4v*)&WL[so * 64 + ((((cl >> 3) ^ (so & 7)) << 3) | (cl & 7))] = pk;
    }
    __syncthreads();
    const int wi = wv & 3, wj = wv >> 2;
    #pragma unroll
    for (int kk = 0; kk < 2; kk++){
      bf16x8 af[4], bf_[4];
      #pragma unroll
      for (int mt = 0; mt < 4; mt++){
        const int o = 64 * wi + 16 * mt + l15;
        af[mt] = *(const bf16x8*)&WL[o * 64 + (((4 * kk + lhi) ^ (o & 7)) << 3)];
      }
      #pragma unroll
      for (int nt = 0; nt < 4; nt++){
        const int n = 64 * wj + 16 * nt + l15;
        bf_[nt] = *(const bf16x8*)&XL[n * 72 + (((4 * kk + lhi) ^ ((n >> 4) & 7)) << 3)];
      }
      #pragma unroll
      for (int mt = 0; mt < 4; mt++)
        #pragma unroll
        for (int nt = 0; nt < 4; nt++)
          acc[mt][nt] = __builtin_amdgcn_mfma_f32_16x16x32_bf16(af[mt], bf_[nt], acc[mt][nt], 0, 0, 0);
    }
  }
  const int wi = wv & 3, wj = wv >> 2;
  const float* imgb = img + (size_t)b * CCH * NTOK;
  float* outb = out + (size_t)b * CCH * NTOK;
  #pragma unroll
  for (int mt = 0; mt < 4; mt++){
    const int ob = 64 * wi + 16 * mt + 4 * lhi;
    #pragma unroll
    for (int nt = 0; nt < 4; nt++){
      const int ng = n0 + 64 * wj + 16 * nt + l15;
      #pragma unroll
      for (int r = 0; r < 4; r++){
        const size_t idx = (size_t)(ob + r) * NTOK + ng;
        outb[idx] = acc[mt][nt][r] + bo[ob + r] + imgb[idx];
      }
    }
  }
}

extern "C" void kernel_launch(void* const* d_in, const int* in_sizes, int n_in,
                              void* d_out, int out_size, void* d_ws, size_t ws_size,
                              hipStream_t stream) {
  const float* img = (const float*)d_in[0];
  const float* msk = (const float*)d_in[1];
  const float* Wq  = (const float*)d_in[2];
  const float* bq  = (const float*)d_in[3];
  const float* Wk  = (const float*)d_in[4];
  const float* bk  = (const float*)d_in[5];
  const float* Wv  = (const float*)d_in[6];
  const float* bv  = (const float*)d_in[7];
  const float* Wo  = (const float*)d_in[8];
  const float* bo  = (const float*)d_in[9];
  float* out = (float*)d_out;

  char* wsb = (char*)d_ws;
  const size_t NE = (size_t)NBATCH * NTOK * CCH;    // elements per [b][n][c] tensor
  short* imgT = (short*)wsb;                         // 2*NE bytes
  short* mskT = (short*)(wsb + 2 * NE);              // 2*NE bytes
  unsigned char* Q8 = (unsigned char*)(wsb + 4 * NE);      // NE bytes
  unsigned char* K8 = (unsigned char*)(wsb + 5 * NE);      // NE bytes
  short* Vn = (short*)(wsb + 6 * NE);                // 2*NE bytes
  short* Wb = (short*)(wsb + 8 * NE);                // 512 KB
  float* lsumg = (float*)(wsb + 8 * NE + 4 * 65536 * 2);   // 2*16*2304 f32
  short* Op = (short*)wsb;                           // aliases imgT+mskT (dead after proj)

  cw_kernel<<<dim3(256), dim3(256), 0, stream>>>(Wq, Wk, Wv, Wo, Wb);
  prep_kernel<<<dim3(36, 4, 32), dim3(256), 0, stream>>>(img, msk, imgT, mskT);
  proj_kernel<<<dim3(36, 3, 16), dim3(256), 0, stream>>>(imgT, mskT, Wb, bq, bk, bv, Q8, K8, Vn);
  attn_kernel<<<dim3(1152), dim3(256), 0, stream>>>(Q8, K8, Vn, Op, lsumg);
  final_kernel<<<dim3(18, 16), dim3(512), 0, stream>>>(Wo, bo, Op, lsumg, img, out);
}

// Round 15
// 237.719 us; speedup vs baseline: 2.5563x; 2.5563x over previous
//
#include <hip/hip_runtime.h>

#define NBATCH 16
#define CCH 256
#define NTOK 2304

typedef __attribute__((ext_vector_type(8))) short bf16x8;
typedef __attribute__((ext_vector_type(4))) short bf16x4v;
typedef __attribute__((ext_vector_type(4))) float f32x4;

__device__ __forceinline__ short f2bf(float x){
  unsigned u = __builtin_bit_cast(unsigned, x);
  u = u + 0x7FFFu + ((u >> 16) & 1u);
  return (short)(u >> 16);
}
__device__ __forceinline__ float bf2f(short h){
  unsigned u = ((unsigned)(unsigned short)h) << 16;
  return __builtin_bit_cast(float, u);
}
__device__ __forceinline__ unsigned char f2fp8(float v){
  return (unsigned char)(__builtin_amdgcn_cvt_pk_fp8_f32(v, v, 0, false) & 0xff);
}

__device__ __forceinline__ void gld_lds16(const void* g, void* l){
  __builtin_amdgcn_global_load_lds((const __attribute__((address_space(1))) void*)g,
                                   (__attribute__((address_space(3))) void*)l, 16, 0, 0);
}

// ---------------- weights fp32 -> bf16 ----------------
__global__ __launch_bounds__(256) void cw_kernel(const float* __restrict__ Wq, const float* __restrict__ Wk,
                                                 const float* __restrict__ Wv, const float* __restrict__ Wo,
                                                 short* __restrict__ out){
  int idx = blockIdx.x * 256 + threadIdx.x;
  int which = idx >> 14;
  int off = idx & 16383;
  const float* src = which==0 ? Wq : which==1 ? Wk : which==2 ? Wv : Wo;
  float4 v = ((const float4*)src)[off];
  bf16x4v pk = { f2bf(v.x), f2bf(v.y), f2bf(v.z), f2bf(v.w) };
  *(bf16x4v*)(out + ((size_t)which << 16) + ((size_t)off << 2)) = pk;
}

// ---------------- transpose+convert [C][N] f32 -> [N][C] bf16 ----------------
__global__ __launch_bounds__(256) void prep_kernel(const float* __restrict__ img, const float* __restrict__ msk,
                                                   short* __restrict__ imgT, short* __restrict__ mskT){
  int zz = blockIdx.z; int b = zz >> 1; int which = zz & 1;
  const float* src = (which ? msk : img) + (size_t)b * CCH * NTOK;
  short* dst = (which ? mskT : imgT) + (size_t)b * NTOK * CCH;
  int n0 = blockIdx.x * 64, c0 = blockIdx.y * 64;
  __shared__ __align__(16) short tile[64][72];
  int tid = threadIdx.x;
  int r = tid >> 2, g = tid & 3;
  const float* p = src + (size_t)(c0 + r) * NTOK + n0 + 16 * g;
  #pragma unroll
  for (int q4 = 0; q4 < 4; q4++){
    float4 v = *(const float4*)(p + 4 * q4);
    tile[16*g + 4*q4 + 0][r] = f2bf(v.x);
    tile[16*g + 4*q4 + 1][r] = f2bf(v.y);
    tile[16*g + 4*q4 + 2][r] = f2bf(v.z);
    tile[16*g + 4*q4 + 3][r] = f2bf(v.w);
  }
  __syncthreads();
  short* qp = dst + (size_t)(n0 + r) * CCH + c0 + 16 * g;
  *(bf16x8*)qp = *(const bf16x8*)&tile[r][16*g];
  *(bf16x8*)(qp + 8) = *(const bf16x8*)&tile[r][16*g + 8];
}

// ---------------- 128x128 GEMM core ----------------
__device__ __forceinline__ void gemm128(const short* __restrict__ Ablk, const short* __restrict__ Bblk,
                                        short* As, short* Bs, f32x4 (&acc)[4][4]){
  const int tid = threadIdx.x;
  const int l = tid & 63, w = tid >> 6;
  const int l15 = l & 15, lhi = l >> 4;
  const int wi = w >> 1, wj = w & 1;
  const int srow = tid >> 3, scs = tid & 7;
  const f32x4 z4 = {0.f, 0.f, 0.f, 0.f};
  #pragma unroll
  for (int mt = 0; mt < 4; mt++)
    #pragma unroll
    for (int nt = 0; nt < 4; nt++) acc[mt][nt] = z4;

  #pragma unroll 1
  for (int kt = 0; kt < 4; kt++){
    const int k0 = kt * 64;
    bf16x8 ra[4], rb[4];
    #pragma unroll
    for (int p = 0; p < 4; p++){
      const int row = p * 32 + srow;
      ra[p] = *(const bf16x8*)(Ablk + (size_t)row * CCH + k0 + 8 * scs);
      rb[p] = *(const bf16x8*)(Bblk + (size_t)row * CCH + k0 + 8 * scs);
    }
    __syncthreads();
    #pragma unroll
    for (int p = 0; p < 4; p++){
      const int row = p * 32 + srow;
      const int sw = (scs ^ (row & 7)) << 3;
      *(bf16x8*)(As + row * 64 + sw) = ra[p];
      *(bf16x8*)(Bs + row * 64 + sw) = rb[p];
    }
    __syncthreads();
    #pragma unroll
    for (int kk = 0; kk < 2; kk++){
      bf16x8 afr[4], bfr[4];
      #pragma unroll
      for (int mt = 0; mt < 4; mt++){
        const int row = 64 * wi + 16 * mt + l15;
        const int ch = 4 * kk + lhi;
        afr[mt] = *(const bf16x8*)(As + row * 64 + ((ch ^ (row & 7)) << 3));
      }
      #pragma unroll
      for (int nt = 0; nt < 4; nt++){
        const int row = 64 * wj + 16 * nt + l15;
        const int ch = 4 * kk + lhi;
        bfr[nt] = *(const bf16x8*)(Bs + row * 64 + ((ch ^ (row & 7)) << 3));
      }
      #pragma unroll
      for (int mt = 0; mt < 4; mt++)
        #pragma unroll
        for (int nt = 0; nt < 4; nt++)
          acc[mt][nt] = __builtin_amdgcn_mfma_f32_16x16x32_bf16(afr[mt], bfr[nt], acc[mt][nt], 0, 0, 0);
    }
  }
}

// ---------------- QKV projections ----------------
// Q/K outputs are fp8 e4m3 (natural scale; 1/sqrt(C)*log2e applied in attn exp2).
__global__ __launch_bounds__(256) void proj_kernel(const short* __restrict__ imgT, const short* __restrict__ mskT,
                                                   const short* __restrict__ Wb,
                                                   const float* __restrict__ bq, const float* __restrict__ bk,
                                                   const float* __restrict__ bv,
                                                   unsigned char* __restrict__ Q8, unsigned char* __restrict__ K8,
                                                   short* __restrict__ Vn){
  __shared__ __align__(16) short As[128 * 64];
  __shared__ __align__(16) short Bs[128 * 64];
  const int b = blockIdx.z, which = blockIdx.y, bx = blockIdx.x;
  const size_t nbT = (size_t)b * NTOK * CCH;
  const short* Ablk; const short* Bblk; const float* bias;
  int ti, tj;
  if (which == 0){
    ti = bx >> 1; tj = bx & 1;
    Ablk = mskT + nbT + (size_t)ti * 128 * CCH;
    Bblk = Wb + (size_t)tj * 128 * CCH;
    bias = bq;
  } else if (which == 1){
    ti = bx >> 1; tj = bx & 1;
    Ablk = imgT + nbT + (size_t)ti * 128 * CCH;
    Bblk = Wb + 65536 + (size_t)tj * 128 * CCH;
    bias = bk;
  } else {
    ti = bx / 18; tj = bx % 18;
    Ablk = Wb + 2 * 65536 + (size_t)ti * 128 * CCH;
    Bblk = imgT + nbT + (size_t)tj * 128 * CCH;
    bias = bv;
  }
  f32x4 acc[4][4];
  gemm128(Ablk, Bblk, As, Bs, acc);
  const int l = threadIdx.x & 63, w = threadIdx.x >> 6;
  const int l15 = l & 15, lhi = l >> 4, wi = w >> 1, wj = w & 1;
  if (which < 2){
    unsigned char* o8 = (which == 0 ? Q8 : K8) + nbT;
    #pragma unroll
    for (int mt = 0; mt < 4; mt++){
      const int i0 = ti * 128 + 64 * wi + 16 * mt + 4 * lhi;
      #pragma unroll
      for (int nt = 0; nt < 4; nt++){
        const int j = tj * 128 + 64 * wj + 16 * nt + l15;
        const float bj = bias[j];
        #pragma unroll
        for (int r = 0; r < 4; r++)
          o8[(size_t)(i0 + r) * CCH + j] = f2fp8(acc[mt][nt][r] + bj);
      }
    }
  } else {
    short* outp = Vn + nbT;
    #pragma unroll
    for (int mt = 0; mt < 4; mt++){
      const int i0 = ti * 128 + 64 * wi + 16 * mt + 4 * lhi;
      #pragma unroll
      for (int nt = 0; nt < 4; nt++){
        const int j = tj * 128 + 64 * wj + 16 * nt + l15;
        #pragma unroll
        for (int r = 0; r < 4; r++)
          outp[(size_t)(i0 + r) * NTOK + j] = f2bf(acc[mt][nt][r] + bias[i0 + r]);
      }
    }
  }
}

// ---------------- attention: fp8 swapped-QK^T, K double-buffer, split-KV x2 ----------------
// Same 2-sync R5 skeleton; K staged into alternating buffers with the issue at the
// TOP of the tile (after sync1) so stage latency is covered by V-load+QK+softmax
// before sync2's vmcnt drain. P packed via v_cvt_pk_bf16_f32 (register-only asm).
// PLAIN __launch_bounds__(256): the (256,4) variant capped VGPR at 64 and spilled
// catastrophically (R14: 550us, 1.8GB spill traffic). Empirical gfx950 rule:
// 2nd arg caps VGPR ~= 256/min_waves_per_EU -- do not use it here.
__global__ __launch_bounds__(256) void attn_kernel(const unsigned char* __restrict__ Q8,
                                                   const unsigned char* __restrict__ K8,
                                                   const short* __restrict__ Vn,
                                                   short* __restrict__ Opart, float* __restrict__ lsumg){
  const int phys = blockIdx.x;
  const int L = (phys & 7) * 144 + (phys >> 3);   // 1152 = 8*144; 144 = 2 batches/XCD
  const int b = L / 72;
  const int rem = L % 72;
  const int half = rem / 36;
  const int q0 = (rem % 36) * 64;
  const int t0 = half * 18;
  const int tid = threadIdx.x, w = tid >> 6, l = tid & 63;
  const int l15 = l & 15, lhi = l >> 4;
  const unsigned char* Qb = Q8 + (size_t)b * NTOK * CCH;
  const unsigned char* Kb = K8 + (size_t)b * NTOK * CCH;
  const short* Vb = Vn + (size_t)b * CCH * NTOK;
  __shared__ __align__(16) unsigned char Ks8[2][64 * 256];  // 32 KB (fp8, dbuf)
  __shared__ __align__(16) short P_lds[64 * 64];            // 8 KB; total 40960 B

  const float SCL = 0.0625f * 1.44269504088896f;  // 1/sqrt(256) * log2(e)
  const int rs2 = (l15 & 7) << 1;                 // QK read row-swizzle (row&7 == l15&7)

  // Q fp8 fragments in registers (16 VGPR)
  long qf[8];
  {
    const unsigned char* qrow = Qb + (size_t)(q0 + 16 * w + l15) * CCH + 8 * lhi;
    #pragma unroll
    for (int kk = 0; kk < 8; kk++) qf[kk] = *(const long*)(qrow + 32 * kk);
  }
  const f32x4 z4 = {0.f, 0.f, 0.f, 0.f};
  f32x4 oacc[4][4];
  #pragma unroll
  for (int qt = 0; qt < 4; qt++)
    #pragma unroll
    for (int ct = 0; ct < 4; ct++) oacc[qt][ct] = z4;
  float lpart = 0.f;

  // stage: 16 slots x 1KB; slot covers rows 4s..4s+3; lane l -> row 4s+(l>>4),
  // src 16B-chunk c16 = (l&15) ^ (row&7); dest linear (rule 21).
#define STAGE_K(BUF, M0) do { \
    _Pragma("unroll") \
    for (int r = 0; r < 4; r++){ \
      const int slot = 4 * r + w; \
      const int row = 4 * slot + (l >> 4); \
      const int c16 = (l & 15) ^ (row & 7); \
      gld_lds16(Kb + (size_t)((M0) + row) * CCH + (c16 << 4), &Ks8[BUF][slot * 1024]); \
    } } while(0)

  STAGE_K(0, t0 * 64);

  int cur = 0;
  #pragma unroll 1
  for (int t = t0; t < t0 + 18; t++){
    const int m0 = t * 64;
    __syncthreads();   // sync1: K(t) staged; Ks[cur^1] free of prior readers

    // issue stage of K(t+1) into the other buffer: covered by V-load+QK+softmax
    if (t + 1 < t0 + 18) STAGE_K(cur ^ 1, m0 + 64);

    // prefetch V tile (bf16) into registers
    bf16x8 vfp[8];
    #pragma unroll
    for (int km = 0; km < 2; km++)
      #pragma unroll
      for (int ct = 0; ct < 4; ct++)
        vfp[4 * km + ct] = *(const bf16x8*)(Vb + (size_t)(64 * w + 16 * ct + l15) * NTOK + m0 + 32 * km + 8 * lhi);

    // S^T = K·Q^T (fp8, swapped operands): lane holds S[m=16mjb+4lhi+r][q=l15]
    const unsigned char* Kc = &Ks8[cur][0];
    f32x4 sacc[4] = {z4, z4, z4, z4};
    __builtin_amdgcn_s_setprio(1);
    #pragma unroll
    for (int mjb = 0; mjb < 4; mjb++){
      const int row = 16 * mjb + l15;
      #pragma unroll
      for (int kk = 0; kk < 8; kk++){
        const int c8 = (4 * kk + lhi) ^ rs2;
        long kf = *(const long*)(Kc + row * 256 + (c8 << 3));
        sacc[mjb] = __builtin_amdgcn_mfma_f32_16x16x32_fp8_fp8(kf, qf[kk], sacc[mjb], 0, 0, 0);
      }
    }
    __builtin_amdgcn_s_setprio(0);
    // P = exp2(s*SCL); in-lane partial row sum; packed b64 write via v_cvt_pk_bf16_f32
    {
      const int prow = 16 * w + l15;
      const int rsw = l15 & 7;
      #pragma unroll
      for (int mjb = 0; mjb < 4; mjb++){
        float p0 = exp2f(sacc[mjb][0] * SCL);
        float p1 = exp2f(sacc[mjb][1] * SCL);
        float p2 = exp2f(sacc[mjb][2] * SCL);
        float p3 = exp2f(sacc[mjb][3] * SCL);
        lpart += (p0 + p1) + (p2 + p3);
        unsigned u0, u1;
        asm("v_cvt_pk_bf16_f32 %0, %1, %2" : "=v"(u0) : "v"(p0), "v"(p1));
        asm("v_cvt_pk_bf16_f32 %0, %1, %2" : "=v"(u1) : "v"(p2), "v"(p3));
        uint2 uv = {u0, u1};
        const int ch16 = (2 * mjb + (lhi >> 1)) ^ rsw;
        *(uint2*)&P_lds[prow * 64 + (ch16 << 3) + ((lhi & 1) << 2)] = uv;
      }
    }
    __syncthreads();   // sync2: P visible; all Ks[cur] reads done; stage(t+1) drained

    // O += P · V^T (bf16)
    __builtin_amdgcn_s_setprio(1);
    #pragma unroll
    for (int km = 0; km < 2; km++){
      bf16x8 pf[4];
      #pragma unroll
      for (int qt = 0; qt < 4; qt++){
        const int prow = 16 * qt + l15;
        pf[qt] = *(const bf16x8*)&P_lds[prow * 64 + (((4 * km + lhi) ^ (prow & 7)) << 3)];
      }
      #pragma unroll
      for (int qt = 0; qt < 4; qt++)
        #pragma unroll
        for (int ct = 0; ct < 4; ct++)
          oacc[qt][ct] = __builtin_amdgcn_mfma_f32_16x16x32_bf16(pf[qt], vfp[4 * km + ct], oacc[qt][ct], 0, 0, 0);
    }
    __builtin_amdgcn_s_setprio(0);
    cur ^= 1;
  }
#undef STAGE_K

  const size_t hrow = ((size_t)half * NBATCH + b) * NTOK + q0;
  // q = q0 + 16w + l15; partials live in lanes {l, l^16, l^32, l^48}
  {
    float s = lpart;
    s += __shfl_xor(s, 16);
    s += __shfl_xor(s, 32);
    if (lhi == 0) lsumg[hrow + 16 * w + l15] = s;
  }
  short* Ob = Opart + hrow * CCH;
  #pragma unroll
  for (int qt = 0; qt < 4; qt++)
    #pragma unroll
    for (int ct = 0; ct < 4; ct++)
      #pragma unroll
      for (int r = 0; r < 4; r++)
        Ob[(size_t)(16 * qt + 4 * lhi + r) * CCH + 64 * w + 16 * ct + l15] = f2bf(oacc[qt][ct][r]);
}

// ================= final (fused reduce): out = img + Wo·((O0+O1)/l) + bo =================
__global__ __launch_bounds__(512, 4) void final_kernel(
    const float* __restrict__ Wo, const float* __restrict__ bo,
    const short* __restrict__ Op, const float* __restrict__ ls,
    const float* __restrict__ img, float* __restrict__ out){
  __shared__ __align__(16) short XL[128 * 72];   // combined av tile [n][c]
  __shared__ __align__(16) short WL[256 * 64];
  const int ti = blockIdx.x, b = blockIdx.y;
  const int n0 = ti * 128;
  const int t = threadIdx.x, wv = t >> 6, l = t & 63;
  const int l15 = l & 15, lhi = l >> 4;
  const int sn = t >> 2, sj = t & 3;
  const int so = t >> 1, sh = t & 1;
  const size_t HS = (size_t)NBATCH * NTOK * CCH;
  const size_t row = (size_t)b * NTOK + n0 + sn;
  const float inv = 1.0f / (ls[row] + ls[(size_t)NBATCH * NTOK + row]);

  const f32x4 z4 = {0.f, 0.f, 0.f, 0.f};
  f32x4 acc[4][4];
  #pragma unroll
  for (int mt = 0; mt < 4; mt++)
    #pragma unroll
    for (int nt = 0; nt < 4; nt++) acc[mt][nt] = z4;

  #pragma unroll 1
  for (int kt = 0; kt < 4; kt++){
    const int c0 = kt * 64;
    bf16x8 a0[2], a1[2];
    #pragma unroll
    for (int j = 0; j < 2; j++){
      const int c = c0 + (2 * sj + j) * 8;
      a0[j] = *(const bf16x8*)(Op + row * CCH + c);
      a1[j] = *(const bf16x8*)(Op + HS + row * CCH + c);
    }
    float4 wreg[8];
    #pragma unroll
    for (int q = 0; q < 8; q++)
      wreg[q] = *(const float4*)(Wo + (size_t)so * CCH + c0 + 32 * sh + 4 * q);
    __syncthreads();
    #pragma unroll
    for (int j = 0; j < 2; j++){
      const int ch = 2 * sj + j;
      bf16x8 cb;
      #pragma unroll
      for (int e = 0; e < 8; e++)
        cb[e] = f2bf((bf2f(a0[j][e]) + bf2f(a1[j][e])) * inv);
      *(bf16x8*)&XL[sn * 72 + ((ch ^ ((sn >> 4) & 7)) << 3)] = cb;
    }
    #pragma unroll
    for (int q = 0; q < 8; q++){
      const int cl = 32 * sh + 4 * q;
      bf16x4v pk = { f2bf(wreg[q].x), f2bf(wreg[q].y), f2bf(wreg[q].z), f2bf(wreg[q].w) };
      *(bf16x4v*)&WL[so * 64 + ((((cl >> 3) ^ (so & 7)) << 3) | (cl & 7))] = pk;
    }
    __syncthreads();
    const int wi = wv & 3, wj = wv >> 2;
    #pragma unroll
    for (int kk = 0; kk < 2; kk++){
      bf16x8 af[4], bf_[4];
      #pragma unroll
      for (int mt = 0; mt < 4; mt++){
        const int o = 64 * wi + 16 * mt + l15;
        af[mt] = *(const bf16x8*)&WL[o * 64 + (((4 * kk + lhi) ^ (o & 7)) << 3)];
      }
      #pragma unroll
      for (int nt = 0; nt < 4; nt++){
        const int n = 64 * wj + 16 * nt + l15;
        bf_[nt] = *(const bf16x8*)&XL[n * 72 + (((4 * kk + lhi) ^ ((n >> 4) & 7)) << 3)];
      }
      #pragma unroll
      for (int mt = 0; mt < 4; mt++)
        #pragma unroll
        for (int nt = 0; nt < 4; nt++)
          acc[mt][nt] = __builtin_amdgcn_mfma_f32_16x16x32_bf16(af[mt], bf_[nt], acc[mt][nt], 0, 0, 0);
    }
  }
  const int wi = wv & 3, wj = wv >> 2;
  const float* imgb = img + (size_t)b * CCH * NTOK;
  float* outb = out + (size_t)b * CCH * NTOK;
  #pragma unroll
  for (int mt = 0; mt < 4; mt++){
    const int ob = 64 * wi + 16 * mt + 4 * lhi;
    #pragma unroll
    for (int nt = 0; nt < 4; nt++){
      const int ng = n0 + 64 * wj + 16 * nt + l15;
      #pragma unroll
      for (int r = 0; r < 4; r++){
        const size_t idx = (size_t)(ob + r) * NTOK + ng;
        outb[idx] = acc[mt][nt][r] + bo[ob + r] + imgb[idx];
      }
    }
  }
}

extern "C" void kernel_launch(void* const* d_in, const int* in_sizes, int n_in,
                              void* d_out, int out_size, void* d_ws, size_t ws_size,
                              hipStream_t stream) {
  const float* img = (const float*)d_in[0];
  const float* msk = (const float*)d_in[1];
  const float* Wq  = (const float*)d_in[2];
  const float* bq  = (const float*)d_in[3];
  const float* Wk  = (const float*)d_in[4];
  const float* bk  = (const float*)d_in[5];
  const float* Wv  = (const float*)d_in[6];
  const float* bv  = (const float*)d_in[7];
  const float* Wo  = (const float*)d_in[8];
  const float* bo  = (const float*)d_in[9];
  float* out = (float*)d_out;

  char* wsb = (char*)d_ws;
  const size_t NE = (size_t)NBATCH * NTOK * CCH;    // elements per [b][n][c] tensor
  short* imgT = (short*)wsb;                         // 2*NE bytes
  short* mskT = (short*)(wsb + 2 * NE);              // 2*NE bytes
  unsigned char* Q8 = (unsigned char*)(wsb + 4 * NE);      // NE bytes
  unsigned char* K8 = (unsigned char*)(wsb + 5 * NE);      // NE bytes
  short* Vn = (short*)(wsb + 6 * NE);                // 2*NE bytes
  short* Wb = (short*)(wsb + 8 * NE);                // 512 KB
  float* lsumg = (float*)(wsb + 8 * NE + 4 * 65536 * 2);   // 2*16*2304 f32
  short* Op = (short*)wsb;                           // aliases imgT+mskT (dead after proj)

  cw_kernel<<<dim3(256), dim3(256), 0, stream>>>(Wq, Wk, Wv, Wo, Wb);
  prep_kernel<<<dim3(36, 4, 32), dim3(256), 0, stream>>>(img, msk, imgT, mskT);
  proj_kernel<<<dim3(36, 3, 16), dim3(256), 0, stream>>>(imgT, mskT, Wb, bq, bk, bv, Q8, K8, Vn);
  attn_kernel<<<dim3(1152), dim3(256), 0, stream>>>(Q8, K8, Vn, Op, lsumg);
  final_kernel<<<dim3(18, 16), dim3(512), 0, stream>>>(Wo, bo, Op, lsumg, img, out);
}

// Round 16
// 226.229 us; speedup vs baseline: 2.6861x; 1.0508x over previous
//
#include <hip/hip_runtime.h>

#define NBATCH 16
#define CCH 256
#define NTOK 2304

typedef __attribute__((ext_vector_type(8))) short bf16x8;
typedef __attribute__((ext_vector_type(4))) short bf16x4v;
typedef __attribute__((ext_vector_type(4))) float f32x4;

__device__ __forceinline__ short f2bf(float x){
  unsigned u = __builtin_bit_cast(unsigned, x);
  u = u + 0x7FFFu + ((u >> 16) & 1u);
  return (short)(u >> 16);
}
__device__ __forceinline__ float bf2f(short h){
  unsigned u = ((unsigned)(unsigned short)h) << 16;
  return __builtin_bit_cast(float, u);
}
__device__ __forceinline__ unsigned char f2fp8(float v){
  return (unsigned char)(__builtin_amdgcn_cvt_pk_fp8_f32(v, v, 0, false) & 0xff);
}

__device__ __forceinline__ void gld_lds16(const void* g, void* l){
  __builtin_amdgcn_global_load_lds((const __attribute__((address_space(1))) void*)g,
                                   (__attribute__((address_space(3))) void*)l, 16, 0, 0);
}

// ---------------- weights fp32 -> bf16 ----------------
__global__ __launch_bounds__(256) void cw_kernel(const float* __restrict__ Wq, const float* __restrict__ Wk,
                                                 const float* __restrict__ Wv, const float* __restrict__ Wo,
                                                 short* __restrict__ out){
  int idx = blockIdx.x * 256 + threadIdx.x;
  int which = idx >> 14;
  int off = idx & 16383;
  const float* src = which==0 ? Wq : which==1 ? Wk : which==2 ? Wv : Wo;
  float4 v = ((const float4*)src)[off];
  bf16x4v pk = { f2bf(v.x), f2bf(v.y), f2bf(v.z), f2bf(v.w) };
  *(bf16x4v*)(out + ((size_t)which << 16) + ((size_t)off << 2)) = pk;
}

// ---------------- transpose+convert [C][N] f32 -> [N][C] bf16 ----------------
__global__ __launch_bounds__(256) void prep_kernel(const float* __restrict__ img, const float* __restrict__ msk,
                                                   short* __restrict__ imgT, short* __restrict__ mskT){
  int zz = blockIdx.z; int b = zz >> 1; int which = zz & 1;
  const float* src = (which ? msk : img) + (size_t)b * CCH * NTOK;
  short* dst = (which ? mskT : imgT) + (size_t)b * NTOK * CCH;
  int n0 = blockIdx.x * 64, c0 = blockIdx.y * 64;
  __shared__ __align__(16) short tile[64][72];
  int tid = threadIdx.x;
  int r = tid >> 2, g = tid & 3;
  const float* p = src + (size_t)(c0 + r) * NTOK + n0 + 16 * g;
  #pragma unroll
  for (int q4 = 0; q4 < 4; q4++){
    float4 v = *(const float4*)(p + 4 * q4);
    tile[16*g + 4*q4 + 0][r] = f2bf(v.x);
    tile[16*g + 4*q4 + 1][r] = f2bf(v.y);
    tile[16*g + 4*q4 + 2][r] = f2bf(v.z);
    tile[16*g + 4*q4 + 3][r] = f2bf(v.w);
  }
  __syncthreads();
  short* qp = dst + (size_t)(n0 + r) * CCH + c0 + 16 * g;
  *(bf16x8*)qp = *(const bf16x8*)&tile[r][16*g];
  *(bf16x8*)(qp + 8) = *(const bf16x8*)&tile[r][16*g + 8];
}

// ---------------- 128x128 GEMM core ----------------
__device__ __forceinline__ void gemm128(const short* __restrict__ Ablk, const short* __restrict__ Bblk,
                                        short* As, short* Bs, f32x4 (&acc)[4][4]){
  const int tid = threadIdx.x;
  const int l = tid & 63, w = tid >> 6;
  const int l15 = l & 15, lhi = l >> 4;
  const int wi = w >> 1, wj = w & 1;
  const int srow = tid >> 3, scs = tid & 7;
  const f32x4 z4 = {0.f, 0.f, 0.f, 0.f};
  #pragma unroll
  for (int mt = 0; mt < 4; mt++)
    #pragma unroll
    for (int nt = 0; nt < 4; nt++) acc[mt][nt] = z4;

  #pragma unroll 1
  for (int kt = 0; kt < 4; kt++){
    const int k0 = kt * 64;
    bf16x8 ra[4], rb[4];
    #pragma unroll
    for (int p = 0; p < 4; p++){
      const int row = p * 32 + srow;
      ra[p] = *(const bf16x8*)(Ablk + (size_t)row * CCH + k0 + 8 * scs);
      rb[p] = *(const bf16x8*)(Bblk + (size_t)row * CCH + k0 + 8 * scs);
    }
    __syncthreads();
    #pragma unroll
    for (int p = 0; p < 4; p++){
      const int row = p * 32 + srow;
      const int sw = (scs ^ (row & 7)) << 3;
      *(bf16x8*)(As + row * 64 + sw) = ra[p];
      *(bf16x8*)(Bs + row * 64 + sw) = rb[p];
    }
    __syncthreads();
    #pragma unroll
    for (int kk = 0; kk < 2; kk++){
      bf16x8 afr[4], bfr[4];
      #pragma unroll
      for (int mt = 0; mt < 4; mt++){
        const int row = 64 * wi + 16 * mt + l15;
        const int ch = 4 * kk + lhi;
        afr[mt] = *(const bf16x8*)(As + row * 64 + ((ch ^ (row & 7)) << 3));
      }
      #pragma unroll
      for (int nt = 0; nt < 4; nt++){
        const int row = 64 * wj + 16 * nt + l15;
        const int ch = 4 * kk + lhi;
        bfr[nt] = *(const bf16x8*)(Bs + row * 64 + ((ch ^ (row & 7)) << 3));
      }
      #pragma unroll
      for (int mt = 0; mt < 4; mt++)
        #pragma unroll
        for (int nt = 0; nt < 4; nt++)
          acc[mt][nt] = __builtin_amdgcn_mfma_f32_16x16x32_bf16(afr[mt], bfr[nt], acc[mt][nt], 0, 0, 0);
    }
  }
}

// ---------------- QKV projections ----------------
// Q/K outputs are fp8 e4m3 (natural scale; 1/sqrt(C)*log2e applied in attn exp2).
__global__ __launch_bounds__(256) void proj_kernel(const short* __restrict__ imgT, const short* __restrict__ mskT,
                                                   const short* __restrict__ Wb,
                                                   const float* __restrict__ bq, const float* __restrict__ bk,
                                                   const float* __restrict__ bv,
                                                   unsigned char* __restrict__ Q8, unsigned char* __restrict__ K8,
                                                   short* __restrict__ Vn){
  __shared__ __align__(16) short As[128 * 64];
  __shared__ __align__(16) short Bs[128 * 64];
  const int b = blockIdx.z, which = blockIdx.y, bx = blockIdx.x;
  const size_t nbT = (size_t)b * NTOK * CCH;
  const short* Ablk; const short* Bblk; const float* bias;
  int ti, tj;
  if (which == 0){
    ti = bx >> 1; tj = bx & 1;
    Ablk = mskT + nbT + (size_t)ti * 128 * CCH;
    Bblk = Wb + (size_t)tj * 128 * CCH;
    bias = bq;
  } else if (which == 1){
    ti = bx >> 1; tj = bx & 1;
    Ablk = imgT + nbT + (size_t)ti * 128 * CCH;
    Bblk = Wb + 65536 + (size_t)tj * 128 * CCH;
    bias = bk;
  } else {
    ti = bx / 18; tj = bx % 18;
    Ablk = Wb + 2 * 65536 + (size_t)ti * 128 * CCH;
    Bblk = imgT + nbT + (size_t)tj * 128 * CCH;
    bias = bv;
  }
  f32x4 acc[4][4];
  gemm128(Ablk, Bblk, As, Bs, acc);
  const int l = threadIdx.x & 63, w = threadIdx.x >> 6;
  const int l15 = l & 15, lhi = l >> 4, wi = w >> 1, wj = w & 1;
  if (which < 2){
    unsigned char* o8 = (which == 0 ? Q8 : K8) + nbT;
    #pragma unroll
    for (int mt = 0; mt < 4; mt++){
      const int i0 = ti * 128 + 64 * wi + 16 * mt + 4 * lhi;
      #pragma unroll
      for (int nt = 0; nt < 4; nt++){
        const int j = tj * 128 + 64 * wj + 16 * nt + l15;
        const float bj = bias[j];
        #pragma unroll
        for (int r = 0; r < 4; r++)
          o8[(size_t)(i0 + r) * CCH + j] = f2fp8(acc[mt][nt][r] + bj);
      }
    }
  } else {
    short* outp = Vn + nbT;
    #pragma unroll
    for (int mt = 0; mt < 4; mt++){
      const int i0 = ti * 128 + 64 * wi + 16 * mt + 4 * lhi;
      #pragma unroll
      for (int nt = 0; nt < 4; nt++){
        const int j = tj * 128 + 64 * wj + 16 * nt + l15;
        #pragma unroll
        for (int r = 0; r < 4; r++)
          outp[(size_t)(i0 + r) * NTOK + j] = f2bf(acc[mt][nt][r] + bias[i0 + r]);
      }
    }
  }
}

// ---------------- attention: fp8 swapped-QK^T, single-buffer K (R13 golden), split-KV x2 ----------------
// R13 structure exactly (single 16KB K buffer, stage after sync2), with the ONLY
// change being P packed via v_cvt_pk_bf16_f32 (R15 proved it cuts VALUBusy ~5pts;
// R15's dbuf+early-stage cost ~15us and is NOT carried over).
__global__ __launch_bounds__(256) void attn_kernel(const unsigned char* __restrict__ Q8,
                                                   const unsigned char* __restrict__ K8,
                                                   const short* __restrict__ Vn,
                                                   short* __restrict__ Opart, float* __restrict__ lsumg){
  const int phys = blockIdx.x;
  const int L = (phys & 7) * 144 + (phys >> 3);   // 1152 = 8*144; 144 = 2 batches/XCD
  const int b = L / 72;
  const int rem = L % 72;
  const int half = rem / 36;
  const int q0 = (rem % 36) * 64;
  const int t0 = half * 18;
  const int tid = threadIdx.x, w = tid >> 6, l = tid & 63;
  const int l15 = l & 15, lhi = l >> 4;
  const unsigned char* Qb = Q8 + (size_t)b * NTOK * CCH;
  const unsigned char* Kb = K8 + (size_t)b * NTOK * CCH;
  const short* Vb = Vn + (size_t)b * CCH * NTOK;
  __shared__ __align__(16) unsigned char Ks8[64 * 256];  // 16 KB
  __shared__ __align__(16) short P_lds[64 * 64];         // 8 KB swizzled; total 24576 B

  const float SCL = 0.0625f * 1.44269504088896f;  // 1/sqrt(256) * log2(e)
  const int rs2 = (l15 & 7) << 1;                 // QK read row-swizzle (row&7 == l15&7)

  // Q fp8 fragments in registers (16 VGPR)
  long qf[8];
  {
    const unsigned char* qrow = Qb + (size_t)(q0 + 16 * w + l15) * CCH + 8 * lhi;
    #pragma unroll
    for (int kk = 0; kk < 8; kk++) qf[kk] = *(const long*)(qrow + 32 * kk);
  }
  const f32x4 z4 = {0.f, 0.f, 0.f, 0.f};
  f32x4 oacc[4][4];
  #pragma unroll
  for (int qt = 0; qt < 4; qt++)
    #pragma unroll
    for (int ct = 0; ct < 4; ct++) oacc[qt][ct] = z4;
  float lpart = 0.f;

  // stage: 16 slots x 1KB; slot covers rows 4s..4s+3; lane l -> row 4s+(l>>4),
  // src 16B-chunk c16 = (l&15) ^ (row&7); dest linear (rule 21).
#define STAGE_K(M0) do { \
    _Pragma("unroll") \
    for (int r = 0; r < 4; r++){ \
      const int slot = 4 * r + w; \
      const int row = 4 * slot + (l >> 4); \
      const int c16 = (l & 15) ^ (row & 7); \
      gld_lds16(Kb + (size_t)((M0) + row) * CCH + (c16 << 4), &Ks8[slot * 1024]); \
    } } while(0)

  STAGE_K(t0 * 64);

  #pragma unroll 1
  for (int t = t0; t < t0 + 18; t++){
    const int m0 = t * 64;
    __syncthreads();   // K(t) staged (drains vmcnt) & Ks free of prior readers

    // prefetch V tile (bf16) into registers
    bf16x8 vfp[8];
    #pragma unroll
    for (int km = 0; km < 2; km++)
      #pragma unroll
      for (int ct = 0; ct < 4; ct++)
        vfp[4 * km + ct] = *(const bf16x8*)(Vb + (size_t)(64 * w + 16 * ct + l15) * NTOK + m0 + 32 * km + 8 * lhi);

    // S^T = K·Q^T (fp8, swapped operands): lane holds S[m=16mjb+4lhi+r][q=l15]
    f32x4 sacc[4] = {z4, z4, z4, z4};
    __builtin_amdgcn_s_setprio(1);
    #pragma unroll
    for (int mjb = 0; mjb < 4; mjb++){
      const int row = 16 * mjb + l15;
      #pragma unroll
      for (int kk = 0; kk < 8; kk++){
        const int c8 = (4 * kk + lhi) ^ rs2;
        long kf = *(const long*)(Ks8 + row * 256 + (c8 << 3));
        sacc[mjb] = __builtin_amdgcn_mfma_f32_16x16x32_fp8_fp8(kf, qf[kk], sacc[mjb], 0, 0, 0);
      }
    }
    __builtin_amdgcn_s_setprio(0);
    // P = exp2(s*SCL); in-lane partial row sum; packed b64 write via v_cvt_pk_bf16_f32
    {
      const int prow = 16 * w + l15;
      const int rsw = l15 & 7;
      #pragma unroll
      for (int mjb = 0; mjb < 4; mjb++){
        float p0 = exp2f(sacc[mjb][0] * SCL);
        float p1 = exp2f(sacc[mjb][1] * SCL);
        float p2 = exp2f(sacc[mjb][2] * SCL);
        float p3 = exp2f(sacc[mjb][3] * SCL);
        lpart += (p0 + p1) + (p2 + p3);
        unsigned u0, u1;
        asm("v_cvt_pk_bf16_f32 %0, %1, %2" : "=v"(u0) : "v"(p0), "v"(p1));
        asm("v_cvt_pk_bf16_f32 %0, %1, %2" : "=v"(u1) : "v"(p2), "v"(p3));
        uint2 uv = {u0, u1};
        const int ch16 = (2 * mjb + (lhi >> 1)) ^ rsw;
        *(uint2*)&P_lds[prow * 64 + (ch16 << 3) + ((lhi & 1) << 2)] = uv;
      }
    }
    __syncthreads();   // P visible AND all Ks reads done

    if (t + 1 < t0 + 18) STAGE_K(m0 + 64);

    // O += P · V^T (bf16)
    __builtin_amdgcn_s_setprio(1);
    #pragma unroll
    for (int km = 0; km < 2; km++){
      bf16x8 pf[4];
      #pragma unroll
      for (int qt = 0; qt < 4; qt++){
        const int prow = 16 * qt + l15;
        pf[qt] = *(const bf16x8*)&P_lds[prow * 64 + (((4 * km + lhi) ^ (prow & 7)) << 3)];
      }
      #pragma unroll
      for (int qt = 0; qt < 4; qt++)
        #pragma unroll
        for (int ct = 0; ct < 4; ct++)
          oacc[qt][ct] = __builtin_amdgcn_mfma_f32_16x16x32_bf16(pf[qt], vfp[4 * km + ct], oacc[qt][ct], 0, 0, 0);
    }
    __builtin_amdgcn_s_setprio(0);
  }
#undef STAGE_K

  const size_t hrow = ((size_t)half * NBATCH + b) * NTOK + q0;
  // q = q0 + 16w + l15; partials live in lanes {l, l^16, l^32, l^48}
  {
    float s = lpart;
    s += __shfl_xor(s, 16);
    s += __shfl_xor(s, 32);
    if (lhi == 0) lsumg[hrow + 16 * w + l15] = s;
  }
  short* Ob = Opart + hrow * CCH;
  #pragma unroll
  for (int qt = 0; qt < 4; qt++)
    #pragma unroll
    for (int ct = 0; ct < 4; ct++)
      #pragma unroll
      for (int r = 0; r < 4; r++)
        Ob[(size_t)(16 * qt + 4 * lhi + r) * CCH + 64 * w + 16 * ct + l15] = f2bf(oacc[qt][ct][r]);
}

// ================= final (fused reduce): out = img + Wo·((O0+O1)/l) + bo =================
__global__ __launch_bounds__(512, 4) void final_kernel(
    const float* __restrict__ Wo, const float* __restrict__ bo,
    const short* __restrict__ Op, const float* __restrict__ ls,
    const float* __restrict__ img, float* __restrict__ out){
  __shared__ __align__(16) short XL[128 * 72];   // combined av tile [n][c]
  __shared__ __align__(16) short WL[256 * 64];
  const int ti = blockIdx.x, b = blockIdx.y;
  const int n0 = ti * 128;
  const int t = threadIdx.x, wv = t >> 6, l = t & 63;
  const int l15 = l & 15, lhi = l >> 4;
  const int sn = t >> 2, sj = t & 3;
  const int so = t >> 1, sh = t & 1;
  const size_t HS = (size_t)NBATCH * NTOK * CCH;
  const size_t row = (size_t)b * NTOK + n0 + sn;
  const float inv = 1.0f / (ls[row] + ls[(size_t)NBATCH * NTOK + row]);

  const f32x4 z4 = {0.f, 0.f, 0.f, 0.f};
  f32x4 acc[4][4];
  #pragma unroll
  for (int mt = 0; mt < 4; mt++)
    #pragma unroll
    for (int nt = 0; nt < 4; nt++) acc[mt][nt] = z4;

  #pragma unroll 1
  for (int kt = 0; kt < 4; kt++){
    const int c0 = kt * 64;
    bf16x8 a0[2], a1[2];
    #pragma unroll
    for (int j = 0; j < 2; j++){
      const int c = c0 + (2 * sj + j) * 8;
      a0[j] = *(const bf16x8*)(Op + row * CCH + c);
      a1[j] = *(const bf16x8*)(Op + HS + row * CCH + c);
    }
    float4 wreg[8];
    #pragma unroll
    for (int q = 0; q < 8; q++)
      wreg[q] = *(const float4*)(Wo + (size_t)so * CCH + c0 + 32 * sh + 4 * q);
    __syncthreads();
    #pragma unroll
    for (int j = 0; j < 2; j++){
      const int ch = 2 * sj + j;
      bf16x8 cb;
      #pragma unroll
      for (int e = 0; e < 8; e++)
        cb[e] = f2bf((bf2f(a0[j][e]) + bf2f(a1[j][e])) * inv);
      *(bf16x8*)&XL[sn * 72 + ((ch ^ ((sn >> 4) & 7)) << 3)] = cb;
    }
    #pragma unroll
    for (int q = 0; q < 8; q++){
      const int cl = 32 * sh + 4 * q;
      bf16x4v pk = { f2bf(wreg[q].x), f2bf(wreg[q].y), f2bf(wreg[q].z), f2bf(wreg[q].w) };
      *(bf16x4v*)&WL[so * 64 + ((((cl >> 3) ^ (so & 7)) << 3) | (cl & 7))] = pk;
    }
    __syncthreads();
    const int wi = wv & 3, wj = wv >> 2;
    #pragma unroll
    for (int kk = 0; kk < 2; kk++){
      bf16x8 af[4], bf_[4];
      #pragma unroll
      for (int mt = 0; mt < 4; mt++){
        const int o = 64 * wi + 16 * mt + l15;
        af[mt] = *(const bf16x8*)&WL[o * 64 + (((4 * kk + lhi) ^ (o & 7)) << 3)];
      }
      #pragma unroll
      for (int nt = 0; nt < 4; nt++){
        const int n = 64 * wj + 16 * nt + l15;
        bf_[nt] = *(const bf16x8*)&XL[n * 72 + (((4 * kk + lhi) ^ ((n >> 4) & 7)) << 3)];
      }
      #pragma unroll
      for (int mt = 0; mt < 4; mt++)
        #pragma unroll
        for (int nt = 0; nt < 4; nt++)
          acc[mt][nt] = __builtin_amdgcn_mfma_f32_16x16x32_bf16(af[mt], bf_[nt], acc[mt][nt], 0, 0, 0);
    }
  }
  const int wi = wv & 3, wj = wv >> 2;
  const float* imgb = img + (size_t)b * CCH * NTOK;
  float* outb = out + (size_t)b * CCH * NTOK;
  #pragma unroll
  for (int mt = 0; mt < 4; mt++){
    const int ob = 64 * wi + 16 * mt + 4 * lhi;
    #pragma unroll
    for (int nt = 0; nt < 4; nt++){
      const int ng = n0 + 64 * wj + 16 * nt + l15;
      #pragma unroll
      for (int r = 0; r < 4; r++){
        const size_t idx = (size_t)(ob + r) * NTOK + ng;
        outb[idx] = acc[mt][nt][r] + bo[ob + r] + imgb[idx];
      }
    }
  }
}

extern "C" void kernel_launch(void* const* d_in, const int* in_sizes, int n_in,
                              void* d_out, int out_size, void* d_ws, size_t ws_size,
                              hipStream_t stream) {
  const float* img = (const float*)d_in[0];
  const float* msk = (const float*)d_in[1];
  const float* Wq  = (const float*)d_in[2];
  const float* bq  = (const float*)d_in[3];
  const float* Wk  = (const float*)d_in[4];
  const float* bk  = (const float*)d_in[5];
  const float* Wv  = (const float*)d_in[6];
  const float* bv  = (const float*)d_in[7];
  const float* Wo  = (const float*)d_in[8];
  const float* bo  = (const float*)d_in[9];
  float* out = (float*)d_out;

  char* wsb = (char*)d_ws;
  const size_t NE = (size_t)NBATCH * NTOK * CCH;    // elements per [b][n][c] tensor
  short* imgT = (short*)wsb;                         // 2*NE bytes
  short* mskT = (short*)(wsb + 2 * NE);              // 2*NE bytes
  unsigned char* Q8 = (unsigned char*)(wsb + 4 * NE);      // NE bytes
  unsigned char* K8 = (unsigned char*)(wsb + 5 * NE);      // NE bytes
  short* Vn = (short*)(wsb + 6 * NE);                // 2*NE bytes
  short* Wb = (short*)(wsb + 8 * NE);                // 512 KB
  float* lsumg = (float*)(wsb + 8 * NE + 4 * 65536 * 2);   // 2*16*2304 f32
  short* Op = (short*)wsb;                           // aliases imgT+mskT (dead after proj)

  cw_kernel<<<dim3(256), dim3(256), 0, stream>>>(Wq, Wk, Wv, Wo, Wb);
  prep_kernel<<<dim3(36, 4, 32), dim3(256), 0, stream>>>(img, msk, imgT, mskT);
  proj_kernel<<<dim3(36, 3, 16), dim3(256), 0, stream>>>(imgT, mskT, Wb, bq, bk, bv, Q8, K8, Vn);
  attn_kernel<<<dim3(1152), dim3(256), 0, stream>>>(Q8, K8, Vn, Op, lsumg);
  final_kernel<<<dim3(18, 16), dim3(512), 0, stream>>>(Wo, bo, Op, lsumg, img, out);
}